// Round 6
// baseline (147.827 us; speedup 1.0000x reference)
//
#include <hip/hip_runtime.h>

#define NN 6144
#define DD 768
#define NB 48               // 6144 / 128 tile blocks per dim
#define NTILES 1176         // NB*(NB+1)/2 upper-triangular tiles
#define INV_T 14.285714285714286f
#define CMAX  14.285714285714286f

typedef int i32x4 __attribute__((ext_vector_type(4)));
typedef int i32x8 __attribute__((ext_vector_type(8)));
typedef float f32x4_t __attribute__((ext_vector_type(4)));

__device__ __forceinline__ void load_lds16(const void* g, void* l) {
    __builtin_amdgcn_global_load_lds((__attribute__((address_space(1))) void*)g,
                                     (__attribute__((address_space(3))) void*)l,
                                     16, 0, 0);
}

// Kernel 1: L2-normalize rows -> fp8 e4m3 (unit MX scale); zero den/num sums.
// One wave per row; 1536 blocks x 256 threads.
__global__ void norm_kernel(const float* __restrict__ feats,
                            unsigned int* __restrict__ fb8,   // 6144*192 uints
                            float* __restrict__ den_num) {    // [0..NN)=den, [NN..2NN)=num
    const int wid = threadIdx.x >> 6;
    const int lane = threadIdx.x & 63;
    const int row = blockIdx.x * 4 + wid;

    if (threadIdx.x < 8) den_num[blockIdx.x * 8 + threadIdx.x] = 0.0f;

    const float4* src = (const float4*)(feats + (size_t)row * DD);
    float4 v[3];
    float ss = 0.0f;
#pragma unroll
    for (int i = 0; i < 3; ++i) {
        v[i] = src[lane + i * 64];
        ss += v[i].x * v[i].x + v[i].y * v[i].y + v[i].z * v[i].z + v[i].w * v[i].w;
    }
#pragma unroll
    for (int m = 32; m >= 1; m >>= 1) ss += __shfl_xor(ss, m);
    const float sc = 1.0f / fmaxf(sqrtf(ss), 1e-12f);

#pragma unroll
    for (int i = 0; i < 3; ++i) {
        unsigned int w = 0;
        w = __builtin_amdgcn_cvt_pk_fp8_f32(v[i].x * sc, v[i].y * sc, w, 0);
        w = __builtin_amdgcn_cvt_pk_fp8_f32(v[i].z * sc, v[i].w * sc, w, 1);
        fb8[(size_t)row * 192 + lane + i * 64] = w;
    }
}

// Kernel 2: upper-triangular MX-fp8 MFMA Gram tiles + fused exp row/col sums.
//
// r11: 8-WAVE BLOCKS (512 thr) -> 4 waves/SIMD.
//  Evidence: r9 occupancy 18% => avg 5.8 waves/CU => T_block ~ 42k cycles
//  for ~5k cycles of countable work; no pipe >20% busy. Every prior variant
//  ran 2 waves/SIMD (4-wave blocks, 2 blocks/CU): when a block stalls at
//  barrier/vmcnt, the SIMD has at most ONE alternative wave. Structural
//  pipelining (r8 dbuf, r10 counted-vmcnt) moved little because there is
//  no TLP to absorb the residual latency (guide m99/m131-141: source-level
//  pipelining can't beat it; wave-level overlap must).
//  Change: same 128x128 tile, 8 waves in 2x4 grid; per wave 64x32 output
//  (acc 4x2 frags), 8 MFMA + 12 ds_read/step, 4 global_load_lds/thread/
//  stage (vmcnt counts: keep-prefetch = vmcnt(4)). LDS still 64 KB -> 2
//  blocks/CU -> 16 waves/CU = 4/SIMD, double the latency-hiding pool.
//  VGPR ~100 < 128 cap of __launch_bounds__(512,4) -> no spill.
//
// r10 (kept): counted-vmcnt pipeline + raw s_barrier + setprio; ONLY vmcnt
//  ops in the K-loop are the stage loads, so s_waitcnt vmcnt(4) waits the
//  current tile and leaves the prefetch in flight across the barrier.
// r9 (kept): supertile-chunked XCD remap (FETCH 19.3->10.9 MB verified).
// r8 (kept): statically-named ping-pong buffers, rolled loop (no spill).
__global__ __launch_bounds__(512, 4) void gemm_expsum_kernel(
        const unsigned char* __restrict__ fb8,
        float* __restrict__ den_sum, float* __restrict__ num_sum) {
    __shared__ __align__(16) char sA0[128 * 128];
    __shared__ __align__(16) char sA1[128 * 128];
    __shared__ __align__(16) char sB0[128 * 128];
    __shared__ __align__(16) char sB1[128 * 128];

    // ---- supertile-chunked remap: blockIdx -> (bi, bj), bi <= bj ----
    // 4x4 supertile grid of 12x12 panels; each XCD (blockIdx&7) gets one
    // contiguous 147-tile chunk (1176 = 8*147). ALL-ARITHMETIC decode.
    const int chunk = blockIdx.x & 7;
    const int pos   = blockIdx.x >> 3;
    int rem = chunk * 147 + pos;  // position in supertile-ordered list

    int si = 0;
    while (rem >= 510 - 144 * si) { rem -= 510 - 144 * si; ++si; }
    int bi, bj;
    if (rem < 78) {               // diagonal supertile (si,si): 12x12 triangle
        int r = 0;
        while (rem >= 12 - r) { rem -= 12 - r; ++r; }
        bi = si * 12 + r;
        bj = si * 12 + r + rem;
    } else {                      // off-diagonal supertiles, 144 tiles each
        rem -= 78;
        const int sj = si + 1 + rem / 144;
        const int lo = rem % 144;
        bi = si * 12 + lo / 12;
        bj = sj * 12 + lo % 12;
    }

    const bool isdiag = (bi == bj);
    const bool neardiag = (bj - bi) <= 1;
    const int i0 = bi * 128;
    const int j0 = bj * 128;

    const int t = threadIdx.x;
    const int lane = t & 63;
    const int wid = t >> 6;       // 0..7
    const int wm = wid >> 2;      // wave row (0..1): 64-row half
    const int wn = wid & 3;       // wave col (0..3): 32-col quarter

    // staging: thread t -> row = t>>3 (0..63; +64/inst), 16B chunk
    // (t&7)^(row&7) — pre-swizzled global so LDS dest stays linear.
    const int srow = t >> 3;
    const int scb = ((t & 7) ^ (srow & 7)) * 16;
    const unsigned char* gA = fb8 + (size_t)(i0 + srow) * DD + scb;
    const unsigned char* gB = fb8 + (size_t)(j0 + srow) * DD + scb;
    const int ldsoff = wid * 1024;  // wave-uniform base; HW adds lane*16

    f32x4_t acc[4][2];
    const f32x4_t zz = {0.0f, 0.0f, 0.0f, 0.0f};
#pragma unroll
    for (int mi = 0; mi < 4; ++mi)
#pragma unroll
        for (int ni = 0; ni < 2; ++ni) acc[mi][ni] = zz;

    const int q = lane >> 4;
    const int mrow = lane & 15;
    const int x7 = lane & 7;
    const int c0 = ((q << 1) ^ x7) << 4;        // chunk byte offset, k-half 0
    const int c1 = (((q << 1) | 1) ^ x7) << 4;  // k-half 1

// 4 global_load_lds per wave per STAGE — the ONLY vmcnt ops in the K-loop.
// Inst i covers rows 64i..64i+63 (8 rows per wave, lane*16 linear dest).
#define STAGE(dstA, dstB, k0)                                                 \
    {                                                                         \
        _Pragma("unroll")                                                     \
        for (int i = 0; i < 2; ++i) {                                         \
            load_lds16(gA + (size_t)(i * 64) * DD + (k0), (dstA) + i * 8192 + ldsoff); \
            load_lds16(gB + (size_t)(i * 64) * DD + (k0), (dstB) + i * 8192 + ldsoff); \
        }                                                                     \
    }

#define COMPUTE(srcA, srcB)                                                   \
    {                                                                         \
        __builtin_amdgcn_s_setprio(1);                                        \
        i32x8 af[4];                                                          \
        _Pragma("unroll")                                                     \
        for (int mi = 0; mi < 4; ++mi) {                                      \
            const char* p = (srcA) + (wm * 64 + mi * 16 + mrow) * 128;        \
            i32x4 lo = *(const i32x4*)(p + c0);                               \
            i32x4 hi = *(const i32x4*)(p + c1);                               \
            af[mi] = __builtin_shufflevector(lo, hi, 0, 1, 2, 3, 4, 5, 6, 7); \
        }                                                                     \
        _Pragma("unroll")                                                     \
        for (int ni = 0; ni < 2; ++ni) {                                      \
            const char* p = (srcB) + (wn * 32 + ni * 16 + mrow) * 128;        \
            i32x4 lo = *(const i32x4*)(p + c0);                               \
            i32x4 hi = *(const i32x4*)(p + c1);                               \
            i32x8 bf = __builtin_shufflevector(lo, hi, 0, 1, 2, 3, 4, 5, 6, 7); \
            _Pragma("unroll")                                                 \
            for (int mi = 0; mi < 4; ++mi)                                    \
                acc[mi][ni] = __builtin_amdgcn_mfma_scale_f32_16x16x128_f8f6f4( \
                    af[mi], bf, acc[mi][ni], 0, 0,                            \
                    0, 0x7F7F7F7F, 0, 0x7F7F7F7F);                            \
        }                                                                     \
        __builtin_amdgcn_s_setprio(0);                                        \
    }

// Wait for the 4 OLDEST loads (current tile) only; prefetch stays in flight.
#define WAITBAR_KEEP4                                                         \
    asm volatile("s_waitcnt vmcnt(4)" ::: "memory");                          \
    __builtin_amdgcn_s_barrier();

#define WAITBAR_DRAIN                                                         \
    asm volatile("s_waitcnt vmcnt(0)" ::: "memory");                          \
    __builtin_amdgcn_s_barrier();

// Buffer-reuse barrier: compiler fence pins ds_reads; raw s_barrier
// (NO vmcnt drain — that's the r8 disease).
#define ENDBAR                                                                \
    asm volatile("" ::: "memory");                                            \
    __builtin_amdgcn_s_barrier();

    // Prologue: stage tile 0 (4 in flight).
    STAGE(sA0, sB0, 0);

    // Steady state: 2 tiles in flight, wait-oldest-4, one raw barrier pair
    // per K-step. Computes hit k=0,128,256,384; tail does 512,640.
#pragma unroll 1
    for (int kb = 0; kb < 2; ++kb) {
        const int k0 = kb * 256;
        STAGE(sA1, sB1, k0 + 128);   // 8 in flight
        WAITBAR_KEEP4                // tile(k0) landed; prefetch in flight
        COMPUTE(sA0, sB0);           // k = k0
        ENDBAR                       // sA0/sB0 safe to overwrite
        STAGE(sA0, sB0, k0 + 256);   // 8 in flight
        WAITBAR_KEEP4
        COMPUTE(sA1, sB1);           // k = k0 + 128
        ENDBAR
    }
    // Tail: k=512 then k=640.
    STAGE(sA1, sB1, 640);            // 8 in flight
    WAITBAR_KEEP4
    COMPUTE(sA0, sB0);               // k = 512
    WAITBAR_DRAIN                    // drain tile(640); also reuse-barrier
    COMPUTE(sA1, sB1);               // k = 640

#undef STAGE
#undef COMPUTE
#undef WAITBAR_KEEP4
#undef WAITBAR_DRAIN
#undef ENDBAR

    // Epilogue. C/D layout: col=lane&15 (+ni*16), row=(lane>>4)*4+reg (+mi*16).
    // Wave covers rows [wm*64, wm*64+64) x cols [wn*32, wn*32+32).
    const int colb = j0 + wn * 32 + mrow;
    const int rowb = i0 + wm * 64 + (q << 2);
    float cs[2] = {0.f, 0.f};
    float csn[2] = {0.f, 0.f};
#pragma unroll
    for (int mi = 0; mi < 4; ++mi) {
        float rsv[4] = {0.f, 0.f, 0.f, 0.f};
        float rsn[4] = {0.f, 0.f, 0.f, 0.f};
#pragma unroll
        for (int ni = 0; ni < 2; ++ni) {
            const int col = colb + ni * 16;
#pragma unroll
            for (int r = 0; r < 4; ++r) {
                const int row = rowb + mi * 16 + r;
                float e = __expf(__builtin_fmaf(acc[mi][ni][r], INV_T, -CMAX));
                if (isdiag && row == col) e = 0.0f;
                rsv[r] += e;
                cs[ni] += e;
                if (neardiag && (row / 3 == col / 3) && row != col) {
                    rsn[r] += e;
                    csn[ni] += e;
                }
            }
        }
#pragma unroll
        for (int r = 0; r < 4; ++r) {
            float v = rsv[r];
            v += __shfl_xor(v, 8);
            v += __shfl_xor(v, 4);
            v += __shfl_xor(v, 2);
            v += __shfl_xor(v, 1);
            if (mrow == 0) atomicAdd(&den_sum[rowb + mi * 16 + r], v);
        }
        if (neardiag) {
#pragma unroll
            for (int r = 0; r < 4; ++r) {
                float v = rsn[r];
                v += __shfl_xor(v, 8);
                v += __shfl_xor(v, 4);
                v += __shfl_xor(v, 2);
                v += __shfl_xor(v, 1);
                if (mrow == 0) atomicAdd(&num_sum[rowb + mi * 16 + r], v);
            }
        }
    }
    if (!isdiag) {
#pragma unroll
        for (int ni = 0; ni < 2; ++ni) {
            float v = cs[ni];
            v += __shfl_xor(v, 16);
            v += __shfl_xor(v, 32);
            if (q == 0) atomicAdd(&den_sum[colb + ni * 16], v);
        }
        if (neardiag) {
#pragma unroll
            for (int ni = 0; ni < 2; ++ni) {
                float v = csn[ni];
                v += __shfl_xor(v, 16);
                v += __shfl_xor(v, 32);
                if (q == 0) atomicAdd(&num_sum[colb + ni * 16], v);
            }
        }
    }
}

// Kernel 3: loss = mean(log(den) - log(num))  (CMAX cancels). Single block.
__global__ void finalize_kernel(const float* __restrict__ den_sum,
                                const float* __restrict__ num_sum,
                                float* __restrict__ out) {
    float local = 0.0f;
    for (int i = threadIdx.x; i < NN; i += 256) {
        local += logf(den_sum[i]) - logf(num_sum[i]);
    }
#pragma unroll
    for (int m = 32; m >= 1; m >>= 1) local += __shfl_xor(local, m);
    __shared__ float ws[4];
    if ((threadIdx.x & 63) == 0) ws[threadIdx.x >> 6] = local;
    __syncthreads();
    if (threadIdx.x == 0) out[0] = (ws[0] + ws[1] + ws[2] + ws[3]) / (float)NN;
}

extern "C" void kernel_launch(void* const* d_in, const int* in_sizes, int n_in,
                              void* d_out, int out_size, void* d_ws, size_t ws_size,
                              hipStream_t stream) {
    const float* feats = (const float*)d_in[0];
    float* out = (float*)d_out;

    char* ws = (char*)d_ws;
    unsigned int* fb8 = (unsigned int*)ws;                 // 6144*768 = 4718592 B
    float* den_num    = (float*)(ws + 4718592);            // 2*6144*4 B
    float* den_sum    = den_num;
    float* num_sum    = den_num + NN;

    norm_kernel<<<NN / 4, 256, 0, stream>>>(feats, fb8, den_num);
    gemm_expsum_kernel<<<NTILES, 512, 0, stream>>>((const unsigned char*)fb8,
                                                   den_sum, num_sum);
    finalize_kernel<<<1, 256, 0, stream>>>(den_sum, num_sum, out);
}